// Round 1
// baseline (156.002 us; speedup 1.0000x reference)
//
#include <hip/hip_runtime.h>

#define BB 16
#define CIN 256
#define COUT 128
#define EE 512
#define HH 64
#define WW 64

// ws layout (bytes):
//   bias1 [16][256] f32 @ 0        (16384)
//   bias2 [16][128] f32 @ 16384    (8192)
//   bias3 [16][128] f32 @ 24576    (8192)
//   scale [128] f32     @ 32768    (512)
//   A     [128] f32     @ 33280    (512)
//   B0    [128] f32     @ 33792    (512)
//   wpack [128][9][4] u64 @ 34304  (36864)
//   xpack [16][64][64][4] u64 @ 71168 (2097152)

__global__ __launch_bounds__(256) void prep_k(
    const float* __restrict__ emb,
    const float* __restrict__ m1w, const float* __restrict__ m1b,
    const float* __restrict__ m2w, const float* __restrict__ m2b,
    const float* __restrict__ m3w, const float* __restrict__ m3b,
    const float* __restrict__ conv_w,
    float* __restrict__ bias1, float* __restrict__ bias2, float* __restrict__ bias3,
    float* __restrict__ scale, unsigned long long* __restrict__ wpack)
{
    int bid = blockIdx.x;
    int tid = threadIdx.x;
    __shared__ float se[EE];
    __shared__ float red[256];
    if (bid < BB) {
        for (int e = tid; e < EE; e += 256) {
            float v = emb[bid * EE + e];
            se[e] = v / (1.0f + __expf(-v));
        }
        __syncthreads();
        {
            int c = tid;  // 0..255
            float acc = m1b[c];
            const float4* w4 = (const float4*)(m1w + (size_t)c * EE);
            for (int e4 = 0; e4 < EE / 4; ++e4) {
                float4 v = w4[e4];
                acc += se[e4 * 4 + 0] * v.x + se[e4 * 4 + 1] * v.y +
                       se[e4 * 4 + 2] * v.z + se[e4 * 4 + 3] * v.w;
            }
            bias1[bid * CIN + c] = acc;
        }
        if (tid < COUT) {
            int c = tid;
            float acc = m2b[c];
            const float4* w4 = (const float4*)(m2w + (size_t)c * EE);
            for (int e4 = 0; e4 < EE / 4; ++e4) {
                float4 v = w4[e4];
                acc += se[e4 * 4 + 0] * v.x + se[e4 * 4 + 1] * v.y +
                       se[e4 * 4 + 2] * v.z + se[e4 * 4 + 3] * v.w;
            }
            bias2[bid * COUT + c] = acc;
        } else {
            int c = tid - COUT;
            float acc = m3b[c];
            const float4* w4 = (const float4*)(m3w + (size_t)c * EE);
            for (int e4 = 0; e4 < EE / 4; ++e4) {
                float4 v = w4[e4];
                acc += se[e4 * 4 + 0] * v.x + se[e4 * 4 + 1] * v.y +
                       se[e4 * 4 + 2] * v.z + se[e4 * 4 + 3] * v.w;
            }
            bias3[bid * COUT + c] = acc;
        }
    } else {
        int o = bid - BB;      // output channel
        int i = tid;           // input channel 0..255
        float wv[9];
        float asum = 0.f;
        const float* wp = conv_w + ((size_t)o * CIN + i) * 9;
        #pragma unroll
        for (int k = 0; k < 9; ++k) {
            float v = wp[k];
            wv[k] = v;
            asum += fabsf(v);
        }
        int wave = tid >> 6;
        #pragma unroll
        for (int k = 0; k < 9; ++k) {
            unsigned long long m = __ballot(wv[k] > 0.0f);
            if ((tid & 63) == 0) wpack[((size_t)o * 9 + k) * 4 + wave] = m;
        }
        red[tid] = asum;
        __syncthreads();
        for (int s = 128; s > 0; s >>= 1) {
            if (tid < s) red[tid] += red[tid + s];
            __syncthreads();
        }
        if (tid == 0) scale[o] = red[0] * (1.0f / 2304.0f);
    }
}

__global__ __launch_bounds__(128) void pack_k(
    const float* __restrict__ x, const float* __restrict__ bias1,
    const float* __restrict__ scale, const float* __restrict__ conv_b,
    const float* __restrict__ bn_g, const float* __restrict__ bn_b,
    const float* __restrict__ bn_m, const float* __restrict__ bn_v,
    float* __restrict__ A, float* __restrict__ B0,
    unsigned long long* __restrict__ xpack)
{
    int bid = blockIdx.x;
    int tid = threadIdx.x;
    if (bid == BB * (HH / 2)) {  // fold block
        if (tid < COUT) {
            float inv = bn_g[tid] * rsqrtf(bn_v[tid] + 1e-5f);
            A[tid] = scale[tid] * inv;
            B0[tid] = (conv_b[tid] - bn_m[tid]) * inv + bn_b[tid];
        }
        return;
    }
    int b = bid / (HH / 2);
    int h2 = bid % (HH / 2);
    int h = h2 * 2 + (tid >> 6);
    int w = tid & 63;
    __shared__ float sb[CIN];
    for (int c = tid; c < CIN; c += 128) sb[c] = bias1[b * CIN + c];
    __syncthreads();
    const float* xp = x + (size_t)b * CIN * HH * WW + (size_t)h * WW + w;
    unsigned long long m0 = 0, m1 = 0, m2 = 0, m3 = 0;
    for (int c = 0; c < 64; ++c)
        if (xp[(size_t)c * HH * WW] + sb[c] > 0.f) m0 |= 1ull << c;
    for (int c = 0; c < 64; ++c)
        if (xp[(size_t)(c + 64) * HH * WW] + sb[c + 64] > 0.f) m1 |= 1ull << c;
    for (int c = 0; c < 64; ++c)
        if (xp[(size_t)(c + 128) * HH * WW] + sb[c + 128] > 0.f) m2 |= 1ull << c;
    for (int c = 0; c < 64; ++c)
        if (xp[(size_t)(c + 192) * HH * WW] + sb[c + 192] > 0.f) m3 |= 1ull << c;
    size_t base = (((size_t)b * HH + h) * WW + w) * 4;
    xpack[base + 0] = m0;
    xpack[base + 1] = m1;
    xpack[base + 2] = m2;
    xpack[base + 3] = m3;
}

__global__ __launch_bounds__(256) void main_k(
    const unsigned long long* __restrict__ wpack,
    const unsigned long long* __restrict__ xpack,
    const float* __restrict__ x,
    const float* __restrict__ A, const float* __restrict__ B0,
    const float* __restrict__ bias2, const float* __restrict__ bias3,
    const float* __restrict__ prelu_a,
    float* __restrict__ out)
{
    __shared__ unsigned long long wl[COUT * 9 * 4];  // 36 KB
    __shared__ float sA[COUT], sB0[COUT], sb2[COUT], sb3[COUT], spa[COUT];
    int bid = blockIdx.x;
    int b = bid >> 6;
    int h = bid & 63;
    int tid = threadIdx.x;
    for (int i = tid; i < COUT * 9 * 4; i += 256) wl[i] = wpack[i];
    if (tid < COUT) {
        sA[tid] = A[tid];
        sB0[tid] = B0[tid];
        sb2[tid] = bias2[b * COUT + tid];
        sb3[tid] = bias3[b * COUT + tid];
        spa[tid] = prelu_a[tid];
    }
    __syncthreads();
    int w = tid & 63;
    int og = tid >> 6;  // 0..3, wave-uniform

    unsigned long long xr[3][3][4];
    int rv[3], cv[3];
    #pragma unroll
    for (int r = 0; r < 3; ++r) {
        int hh = h + r - 1;
        rv[r] = (hh >= 0 && hh < HH) ? -1 : 0;
        int hc = min(max(hh, 0), HH - 1);
        #pragma unroll
        for (int dw = 0; dw < 3; ++dw) {
            int ww = w + dw - 1;
            if (r == 0) cv[dw] = (ww >= 0 && ww < WW) ? -1 : 0;
            int wc = min(max(ww, 0), WW - 1);
            const unsigned long long* p = xpack + ((((size_t)b * HH + hc) * WW + wc) << 2);
            #pragma unroll
            for (int j = 0; j < 4; ++j) xr[r][dw][j] = p[j];
        }
    }

    #pragma unroll 2
    for (int oo = 0; oo < 32; ++oo) {
        int o = og * 32 + oo;
        int isum = 0;
        #pragma unroll
        for (int r = 0; r < 3; ++r) {
            #pragma unroll
            for (int dw = 0; dw < 3; ++dw) {
                const unsigned long long* wq = &wl[((size_t)(o * 9 + r * 3 + dw)) << 2];
                int p = __popcll(xr[r][dw][0] ^ wq[0]) + __popcll(xr[r][dw][1] ^ wq[1]) +
                        __popcll(xr[r][dw][2] ^ wq[2]) + __popcll(xr[r][dw][3] ^ wq[3]);
                int contrib = 256 - 2 * p;
                isum += (rv[r] & cv[dw]) ? contrib : 0;
            }
        }
        float t = (float)isum * sA[o] + sB0[o];
        float r0 = x[(((size_t)b * CIN + 2 * o) * HH + h) * WW + w];
        float r1 = x[(((size_t)b * CIN + 2 * o + 1) * HH + h) * WW + w];
        t += 0.5f * (r0 + r1) + sb2[o];
        t = t > 0.f ? t : spa[o] * t;
        out[(((size_t)b * COUT + o) * HH + h) * WW + w] = t + sb3[o];
    }
}

extern "C" void kernel_launch(void* const* d_in, const int* in_sizes, int n_in,
                              void* d_out, int out_size, void* d_ws, size_t ws_size,
                              hipStream_t stream) {
    const float* x      = (const float*)d_in[0];
    const float* emb    = (const float*)d_in[1];
    const float* m1w    = (const float*)d_in[2];
    const float* m1b    = (const float*)d_in[3];
    const float* conv_w = (const float*)d_in[4];
    const float* conv_b = (const float*)d_in[5];
    const float* bn_g   = (const float*)d_in[6];
    const float* bn_b   = (const float*)d_in[7];
    const float* bn_m   = (const float*)d_in[8];
    const float* bn_v   = (const float*)d_in[9];
    const float* m2w    = (const float*)d_in[10];
    const float* m2b    = (const float*)d_in[11];
    const float* pa     = (const float*)d_in[12];
    const float* m3w    = (const float*)d_in[13];
    const float* m3b    = (const float*)d_in[14];
    float* out = (float*)d_out;

    char* ws = (char*)d_ws;
    float* bias1 = (float*)(ws + 0);
    float* bias2 = (float*)(ws + 16384);
    float* bias3 = (float*)(ws + 24576);
    float* scale = (float*)(ws + 32768);
    float* Aarr  = (float*)(ws + 33280);
    float* B0arr = (float*)(ws + 33792);
    unsigned long long* wpack = (unsigned long long*)(ws + 34304);
    unsigned long long* xpack = (unsigned long long*)(ws + 71168);

    prep_k<<<BB + COUT, 256, 0, stream>>>(emb, m1w, m1b, m2w, m2b, m3w, m3b, conv_w,
                                          bias1, bias2, bias3, scale, wpack);
    pack_k<<<BB * (HH / 2) + 1, 128, 0, stream>>>(x, bias1, scale, conv_b, bn_g, bn_b,
                                                  bn_m, bn_v, Aarr, B0arr, xpack);
    main_k<<<BB * HH, 256, 0, stream>>>(wpack, xpack, x, Aarr, B0arr, bias2, bias3, pa, out);
}

// Round 2
// 101.686 us; speedup vs baseline: 1.5342x; 1.5342x over previous
//
#include <hip/hip_runtime.h>

#define BB 16
#define CIN 256
#define COUT 128
#define EE 512
#define HH 64
#define WW 64

// ws layout (bytes):
//   bias1 [16][256] f32 @ 0        (16384)
//   bias2 [16][128] f32 @ 16384    (8192)
//   bias3 [16][128] f32 @ 24576    (8192)
//   scale [128] f32     @ 32768    (512)
//   A     [128] f32     @ 33280    (512)
//   B0    [128] f32     @ 33792    (512)
//   wpack [128][9][4] u64 @ 34304  (36864)
//   xpack [16][64][64][4] u64 @ 71168 (2097152)

__global__ __launch_bounds__(256) void prep_k(
    const float* __restrict__ emb,
    const float* __restrict__ m1w, const float* __restrict__ m1b,
    const float* __restrict__ m2w, const float* __restrict__ m2b,
    const float* __restrict__ m3w, const float* __restrict__ m3b,
    const float* __restrict__ conv_w, const float* __restrict__ conv_b,
    const float* __restrict__ bn_g, const float* __restrict__ bn_b,
    const float* __restrict__ bn_m, const float* __restrict__ bn_v,
    float* __restrict__ bias1, float* __restrict__ bias2, float* __restrict__ bias3,
    float* __restrict__ A, float* __restrict__ B0,
    unsigned long long* __restrict__ wpack)
{
    int bid = blockIdx.x;
    int tid = threadIdx.x;
    __shared__ float se[EE];
    __shared__ float red[256];
    if (bid < BB) {
        for (int e = tid; e < EE; e += 256) {
            float v = emb[bid * EE + e];
            se[e] = v / (1.0f + __expf(-v));
        }
        __syncthreads();
        {
            int c = tid;  // 0..255
            float acc = m1b[c];
            const float4* w4 = (const float4*)(m1w + (size_t)c * EE);
            #pragma unroll 8
            for (int e4 = 0; e4 < EE / 4; ++e4) {
                float4 v = w4[e4];
                acc += se[e4 * 4 + 0] * v.x + se[e4 * 4 + 1] * v.y +
                       se[e4 * 4 + 2] * v.z + se[e4 * 4 + 3] * v.w;
            }
            bias1[bid * CIN + c] = acc;
        }
        if (tid < COUT) {
            int c = tid;
            float acc = m2b[c];
            const float4* w4 = (const float4*)(m2w + (size_t)c * EE);
            #pragma unroll 8
            for (int e4 = 0; e4 < EE / 4; ++e4) {
                float4 v = w4[e4];
                acc += se[e4 * 4 + 0] * v.x + se[e4 * 4 + 1] * v.y +
                       se[e4 * 4 + 2] * v.z + se[e4 * 4 + 3] * v.w;
            }
            bias2[bid * COUT + c] = acc;
        } else {
            int c = tid - COUT;
            float acc = m3b[c];
            const float4* w4 = (const float4*)(m3w + (size_t)c * EE);
            #pragma unroll 8
            for (int e4 = 0; e4 < EE / 4; ++e4) {
                float4 v = w4[e4];
                acc += se[e4 * 4 + 0] * v.x + se[e4 * 4 + 1] * v.y +
                       se[e4 * 4 + 2] * v.z + se[e4 * 4 + 3] * v.w;
            }
            bias3[bid * COUT + c] = acc;
        }
    } else {
        int o = bid - BB;      // output channel
        int i = tid;           // input channel 0..255
        float wv[9];
        float asum = 0.f;
        const float* wp = conv_w + ((size_t)o * CIN + i) * 9;
        #pragma unroll
        for (int k = 0; k < 9; ++k) {
            float v = wp[k];
            wv[k] = v;
            asum += fabsf(v);
        }
        int wave = tid >> 6;
        #pragma unroll
        for (int k = 0; k < 9; ++k) {
            unsigned long long m = __ballot(wv[k] > 0.0f);
            if ((tid & 63) == 0) wpack[((size_t)o * 9 + k) * 4 + wave] = m;
        }
        red[tid] = asum;
        __syncthreads();
        for (int s = 128; s > 0; s >>= 1) {
            if (tid < s) red[tid] += red[tid + s];
            __syncthreads();
        }
        if (tid == 0) {
            float sc = red[0] * (1.0f / 2304.0f);
            float inv = bn_g[o] * rsqrtf(bn_v[o] + 1e-5f);
            A[o] = sc * inv;
            B0[o] = (conv_b[o] - bn_m[o]) * inv + bn_b[o];
        }
    }
}

// One block per (b,h) row. 256 threads = 64 w-lanes x 4 channel-quarters.
// Each thread: 64 fully-unrolled independent coalesced loads -> one u64 mask.
__global__ __launch_bounds__(256) void pack_k(
    const float* __restrict__ x, const float* __restrict__ bias1,
    unsigned long long* __restrict__ xpack)
{
    int bid = blockIdx.x;          // b*64 + h
    int b = bid >> 6;
    int h = bid & 63;
    int tid = threadIdx.x;
    int w = tid & 63;
    int q = tid >> 6;              // channel quarter, wave-uniform
    __shared__ float sb[CIN];
    sb[tid] = bias1[b * CIN + tid];
    __syncthreads();
    const float* xp = x + ((size_t)b * CIN + (size_t)q * 64) * (HH * WW) + (size_t)h * WW + w;
    const float* bb = &sb[q * 64];
    unsigned long long m = 0;
    #pragma unroll
    for (int c = 0; c < 64; ++c) {
        if (xp[(size_t)c * (HH * WW)] + bb[c] > 0.f) m |= 1ull << c;
    }
    xpack[((((size_t)b * HH + h) * WW + w) << 2) + q] = m;
}

__global__ __launch_bounds__(256) void main_k(
    const unsigned long long* __restrict__ wpack,
    const unsigned long long* __restrict__ xpack,
    const float* __restrict__ x,
    const float* __restrict__ A, const float* __restrict__ B0,
    const float* __restrict__ bias2, const float* __restrict__ bias3,
    const float* __restrict__ prelu_a,
    float* __restrict__ out)
{
    __shared__ unsigned long long wl[COUT * 9 * 4];  // 36 KB
    __shared__ float sA[COUT], sB0[COUT], sb2[COUT], sb3[COUT], spa[COUT];
    int bid = blockIdx.x;
    int b = bid >> 6;
    int h = bid & 63;
    int tid = threadIdx.x;
    for (int i = tid; i < COUT * 9 * 4; i += 256) wl[i] = wpack[i];
    if (tid < COUT) {
        sA[tid] = A[tid];
        sB0[tid] = B0[tid];
        sb2[tid] = bias2[b * COUT + tid];
        sb3[tid] = bias3[b * COUT + tid];
        spa[tid] = prelu_a[tid];
    }
    __syncthreads();
    int w = tid & 63;
    int og = tid >> 6;  // 0..3, wave-uniform

    unsigned long long xr[3][3][4];
    int rv[3], cv[3];
    #pragma unroll
    for (int r = 0; r < 3; ++r) {
        int hh = h + r - 1;
        rv[r] = (hh >= 0 && hh < HH) ? -1 : 0;
        int hc = min(max(hh, 0), HH - 1);
        #pragma unroll
        for (int dw = 0; dw < 3; ++dw) {
            int ww = w + dw - 1;
            if (r == 0) cv[dw] = (ww >= 0 && ww < WW) ? -1 : 0;
            int wc = min(max(ww, 0), WW - 1);
            const unsigned long long* p = xpack + ((((size_t)b * HH + hc) * WW + wc) << 2);
            #pragma unroll
            for (int j = 0; j < 4; ++j) xr[r][dw][j] = p[j];
        }
    }

    #pragma unroll 8
    for (int oo = 0; oo < 32; ++oo) {
        int o = og * 32 + oo;
        float r0 = x[(((size_t)b * CIN + 2 * o) * HH + h) * WW + w];
        float r1 = x[(((size_t)b * CIN + 2 * o + 1) * HH + h) * WW + w];
        int isum = 0;
        #pragma unroll
        for (int r = 0; r < 3; ++r) {
            #pragma unroll
            for (int dw = 0; dw < 3; ++dw) {
                const unsigned long long* wq = &wl[((size_t)(o * 9 + r * 3 + dw)) << 2];
                int p = __popcll(xr[r][dw][0] ^ wq[0]) + __popcll(xr[r][dw][1] ^ wq[1]) +
                        __popcll(xr[r][dw][2] ^ wq[2]) + __popcll(xr[r][dw][3] ^ wq[3]);
                int contrib = 256 - 2 * p;
                isum += (rv[r] & cv[dw]) & contrib;
            }
        }
        float t = (float)isum * sA[o] + sB0[o];
        t += 0.5f * (r0 + r1) + sb2[o];
        t = t > 0.f ? t : spa[o] * t;
        out[(((size_t)b * COUT + o) * HH + h) * WW + w] = t + sb3[o];
    }
}

extern "C" void kernel_launch(void* const* d_in, const int* in_sizes, int n_in,
                              void* d_out, int out_size, void* d_ws, size_t ws_size,
                              hipStream_t stream) {
    const float* x      = (const float*)d_in[0];
    const float* emb    = (const float*)d_in[1];
    const float* m1w    = (const float*)d_in[2];
    const float* m1b    = (const float*)d_in[3];
    const float* conv_w = (const float*)d_in[4];
    const float* conv_b = (const float*)d_in[5];
    const float* bn_g   = (const float*)d_in[6];
    const float* bn_b   = (const float*)d_in[7];
    const float* bn_m   = (const float*)d_in[8];
    const float* bn_v   = (const float*)d_in[9];
    const float* m2w    = (const float*)d_in[10];
    const float* m2b    = (const float*)d_in[11];
    const float* pa     = (const float*)d_in[12];
    const float* m3w    = (const float*)d_in[13];
    const float* m3b    = (const float*)d_in[14];
    float* out = (float*)d_out;

    char* ws = (char*)d_ws;
    float* bias1 = (float*)(ws + 0);
    float* bias2 = (float*)(ws + 16384);
    float* bias3 = (float*)(ws + 24576);
    float* Aarr  = (float*)(ws + 33280);
    float* B0arr = (float*)(ws + 33792);
    unsigned long long* wpack = (unsigned long long*)(ws + 34304);
    unsigned long long* xpack = (unsigned long long*)(ws + 71168);

    prep_k<<<BB + COUT, 256, 0, stream>>>(emb, m1w, m1b, m2w, m2b, m3w, m3b,
                                          conv_w, conv_b, bn_g, bn_b, bn_m, bn_v,
                                          bias1, bias2, bias3, Aarr, B0arr, wpack);
    pack_k<<<BB * HH, 256, 0, stream>>>(x, bias1, xpack);
    main_k<<<BB * HH, 256, 0, stream>>>(wpack, xpack, x, Aarr, B0arr, bias2, bias3, pa, out);
}

// Round 4
// 97.298 us; speedup vs baseline: 1.6033x; 1.0451x over previous
//
#include <hip/hip_runtime.h>

#define BB 16
#define CIN 256
#define COUT 128
#define EE 512
#define HH 64
#define WW 64

// ws layout (bytes):
//   bias1 [16][256] f32 @ 0        (16384)
//   bias2 [16][128] f32 @ 16384    (8192)
//   bias3 [16][128] f32 @ 24576    (8192)
//   A     [128] f32     @ 33280    (512)
//   B0    [128] f32     @ 33792    (512)
//   wpack [9][128][4] u64 @ 34304  (36864)   (tap-major)
//   xpack [16][64][64][4] u64 @ 71168 (2097152)

__global__ __launch_bounds__(256) void prep_k(
    const float* __restrict__ emb,
    const float* __restrict__ m1w, const float* __restrict__ m1b,
    const float* __restrict__ m2w, const float* __restrict__ m2b,
    const float* __restrict__ m3w, const float* __restrict__ m3b,
    const float* __restrict__ conv_w, const float* __restrict__ conv_b,
    const float* __restrict__ bn_g, const float* __restrict__ bn_b,
    const float* __restrict__ bn_m, const float* __restrict__ bn_v,
    float* __restrict__ bias1, float* __restrict__ bias2, float* __restrict__ bias3,
    float* __restrict__ A, float* __restrict__ B0,
    unsigned long long* __restrict__ wpack)
{
    int bid = blockIdx.x;
    int tid = threadIdx.x;
    __shared__ float se[EE];
    __shared__ float red[256];
    if (bid < BB) {
        for (int e = tid; e < EE; e += 256) {
            float v = emb[bid * EE + e];
            se[e] = v / (1.0f + __expf(-v));
        }
        __syncthreads();
        {
            int c = tid;  // 0..255
            float acc = m1b[c];
            const float4* w4 = (const float4*)(m1w + (size_t)c * EE);
            #pragma unroll 8
            for (int e4 = 0; e4 < EE / 4; ++e4) {
                float4 v = w4[e4];
                acc += se[e4 * 4 + 0] * v.x + se[e4 * 4 + 1] * v.y +
                       se[e4 * 4 + 2] * v.z + se[e4 * 4 + 3] * v.w;
            }
            bias1[bid * CIN + c] = acc;
        }
        if (tid < COUT) {
            int c = tid;
            float acc = m2b[c];
            const float4* w4 = (const float4*)(m2w + (size_t)c * EE);
            #pragma unroll 8
            for (int e4 = 0; e4 < EE / 4; ++e4) {
                float4 v = w4[e4];
                acc += se[e4 * 4 + 0] * v.x + se[e4 * 4 + 1] * v.y +
                       se[e4 * 4 + 2] * v.z + se[e4 * 4 + 3] * v.w;
            }
            bias2[bid * COUT + c] = acc;
        } else {
            int c = tid - COUT;
            float acc = m3b[c];
            const float4* w4 = (const float4*)(m3w + (size_t)c * EE);
            #pragma unroll 8
            for (int e4 = 0; e4 < EE / 4; ++e4) {
                float4 v = w4[e4];
                acc += se[e4 * 4 + 0] * v.x + se[e4 * 4 + 1] * v.y +
                       se[e4 * 4 + 2] * v.z + se[e4 * 4 + 3] * v.w;
            }
            bias3[bid * COUT + c] = acc;
        }
    } else {
        int o = bid - BB;      // output channel
        int i = tid;           // input channel 0..255
        float wv[9];
        float asum = 0.f;
        const float* wp = conv_w + ((size_t)o * CIN + i) * 9;
        #pragma unroll
        for (int k = 0; k < 9; ++k) {
            float v = wp[k];
            wv[k] = v;
            asum += fabsf(v);
        }
        int wave = tid >> 6;
        #pragma unroll
        for (int k = 0; k < 9; ++k) {
            unsigned long long m = __ballot(wv[k] > 0.0f);
            if ((tid & 63) == 0) wpack[((size_t)k * COUT + o) * 4 + wave] = m;
        }
        red[tid] = asum;
        __syncthreads();
        for (int s = 128; s > 0; s >>= 1) {
            if (tid < s) red[tid] += red[tid + s];
            __syncthreads();
        }
        if (tid == 0) {
            float sc = red[0] * (1.0f / 2304.0f);
            float inv = bn_g[o] * rsqrtf(bn_v[o] + 1e-5f);
            A[o] = sc * inv;
            B0[o] = (conv_b[o] - bn_m[o]) * inv + bn_b[o];
        }
    }
}

// One block per (b,h) row. 256 threads = 64 w-lanes x 4 channel-quarters.
__global__ __launch_bounds__(256) void pack_k(
    const float* __restrict__ x, const float* __restrict__ bias1,
    unsigned long long* __restrict__ xpack)
{
    int bid = blockIdx.x;          // b*64 + h
    int b = bid >> 6;
    int h = bid & 63;
    int tid = threadIdx.x;
    int w = tid & 63;
    int q = tid >> 6;              // channel quarter, wave-uniform
    __shared__ float sb[CIN];
    sb[tid] = bias1[b * CIN + tid];
    __syncthreads();
    const float* xp = x + ((size_t)b * CIN + (size_t)q * 64) * (HH * WW) + (size_t)h * WW + w;
    const float* bb = &sb[q * 64];
    unsigned long long m = 0;
    #pragma unroll
    for (int c = 0; c < 64; ++c) {
        if (xp[(size_t)c * (HH * WW)] + bb[c] > 0.f) m |= 1ull << c;
    }
    xpack[((((size_t)b * HH + h) * WW + w) << 2) + q] = m;
}

// 2048 blocks: bid = b*128 + h*2 + half. 256 threads = 64 w x 4 og-waves.
// Each thread: 16 output channels. Weights via wave-uniform scalar loads.
__global__ __launch_bounds__(256, 8) void main_k(
    const unsigned long long* __restrict__ wpack,   // [9][128][4]
    const unsigned long long* __restrict__ xpack,   // [16][64][64][4]
    const float* __restrict__ x,
    const float* __restrict__ A, const float* __restrict__ B0,
    const float* __restrict__ bias2, const float* __restrict__ bias3,
    const float* __restrict__ prelu_a,
    float* __restrict__ out)
{
    int bid = blockIdx.x;
    int half = bid & 1;
    int h = (bid >> 1) & 63;
    int b = bid >> 7;
    int tid = threadIdx.x;
    int w = tid & 63;
    int og = tid >> 6;
    int ou = __builtin_amdgcn_readfirstlane(half * 64 + og * 16);  // uniform o base

    int P[16];
    #pragma unroll
    for (int i = 0; i < 16; ++i) P[i] = 0;

    int cm0 = (w >= 1) ? -1 : 0;
    int cm2 = (w <= 62) ? -1 : 0;
    int cntc = 1 - cm0 - cm2;  // (w>=1) + 1 + (w<=62)
    int cntr = 0;

    #pragma unroll
    for (int r = 0; r < 3; ++r) {
        int hh = h + r - 1;
        if (hh < 0 || hh >= HH) continue;  // block-uniform branch
        cntr++;
        #pragma unroll
        for (int dw = 0; dw < 3; ++dw) {
            int wc = min(max(w + dw - 1, 0), WW - 1);
            const unsigned long long* xp =
                xpack + ((((size_t)b * HH + hh) * WW + wc) << 2);
            unsigned long long x0 = xp[0], x1 = xp[1], x2 = xp[2], x3 = xp[3];
            int msk = (dw == 0) ? cm0 : (dw == 2) ? cm2 : -1;
            const unsigned long long* wp =
                wpack + (((size_t)(r * 3 + dw) * COUT + ou) << 2);
            #pragma unroll
            for (int oo = 0; oo < 16; ++oo) {
                int p = __popcll(x0 ^ wp[oo * 4 + 0]) + __popcll(x1 ^ wp[oo * 4 + 1]) +
                        __popcll(x2 ^ wp[oo * 4 + 2]) + __popcll(x3 ^ wp[oo * 4 + 3]);
                if (dw == 1) P[oo] += p;
                else         P[oo] += msk & p;
            }
        }
    }
    int nv = cntr * cntc;

    #pragma unroll
    for (int oo = 0; oo < 16; ++oo) {
        int o = ou + oo;  // uniform
        float t = (float)(nv * 256 - 2 * P[oo]) * A[o] + B0[o];
        float r0 = x[(((size_t)b * CIN + 2 * o) * HH + h) * WW + w];
        float r1 = x[(((size_t)b * CIN + 2 * o + 1) * HH + h) * WW + w];
        t += 0.5f * (r0 + r1) + bias2[b * COUT + o];
        t = t > 0.f ? t : prelu_a[o] * t;
        out[(((size_t)b * COUT + o) * HH + h) * WW + w] = t + bias3[b * COUT + o];
    }
}

extern "C" void kernel_launch(void* const* d_in, const int* in_sizes, int n_in,
                              void* d_out, int out_size, void* d_ws, size_t ws_size,
                              hipStream_t stream) {
    const float* x      = (const float*)d_in[0];
    const float* emb    = (const float*)d_in[1];
    const float* m1w    = (const float*)d_in[2];
    const float* m1b    = (const float*)d_in[3];
    const float* conv_w = (const float*)d_in[4];
    const float* conv_b = (const float*)d_in[5];
    const float* bn_g   = (const float*)d_in[6];
    const float* bn_b   = (const float*)d_in[7];
    const float* bn_m   = (const float*)d_in[8];
    const float* bn_v   = (const float*)d_in[9];
    const float* m2w    = (const float*)d_in[10];
    const float* m2b    = (const float*)d_in[11];
    const float* pa     = (const float*)d_in[12];
    const float* m3w    = (const float*)d_in[13];
    const float* m3b    = (const float*)d_in[14];
    float* out = (float*)d_out;

    char* ws = (char*)d_ws;
    float* bias1 = (float*)(ws + 0);
    float* bias2 = (float*)(ws + 16384);
    float* bias3 = (float*)(ws + 24576);
    float* Aarr  = (float*)(ws + 33280);
    float* B0arr = (float*)(ws + 33792);
    unsigned long long* wpack = (unsigned long long*)(ws + 34304);
    unsigned long long* xpack = (unsigned long long*)(ws + 71168);

    prep_k<<<BB + COUT, 256, 0, stream>>>(emb, m1w, m1b, m2w, m2b, m3w, m3b,
                                          conv_w, conv_b, bn_g, bn_b, bn_m, bn_v,
                                          bias1, bias2, bias3, Aarr, B0arr, wpack);
    pack_k<<<BB * HH, 256, 0, stream>>>(x, bias1, xpack);
    main_k<<<BB * HH * 2, 256, 0, stream>>>(wpack, xpack, x, Aarr, B0arr,
                                            bias2, bias3, pa, out);
}

// Round 5
// 73.595 us; speedup vs baseline: 2.1197x; 1.3221x over previous
//
#include <hip/hip_runtime.h>

#define BB 16
#define CIN 256
#define COUT 128
#define EE 512
#define HH 64
#define WW 64

// ws layout (bytes):
//   bias1 [16][256] f32 @ 0        (16384)
//   bias2 [16][128] f32 @ 16384    (8192)
//   bias3 [16][128] f32 @ 24576    (8192)
//   A     [128] f32     @ 33280    (512)
//   B0    [128] f32     @ 33792    (512)
//   wpack [128][9][4] u64 @ 34304  (36864)   (o-major)
//   xpack [16][64][64][4] u64 @ 71168 (2097152)

// grid: 128 bias-chunk blocks (b*8+chunk) + 128 weight blocks.
__global__ __launch_bounds__(256) void prep_k(
    const float* __restrict__ emb,
    const float* __restrict__ m1w, const float* __restrict__ m1b,
    const float* __restrict__ m2w, const float* __restrict__ m2b,
    const float* __restrict__ m3w, const float* __restrict__ m3b,
    const float* __restrict__ conv_w, const float* __restrict__ conv_b,
    const float* __restrict__ bn_g, const float* __restrict__ bn_b,
    const float* __restrict__ bn_m, const float* __restrict__ bn_v,
    float* __restrict__ bias1, float* __restrict__ bias2, float* __restrict__ bias3,
    float* __restrict__ A, float* __restrict__ B0,
    unsigned long long* __restrict__ wpack)
{
    int bid = blockIdx.x;
    int tid = threadIdx.x;
    __shared__ float red[256];
    if (bid < 128) {
        // bias dot-products: b = bid>>3, chunk = bid&7
        int b = bid >> 3;
        int chunk = bid & 7;
        __shared__ float se[EE];
        se[tid]       = 0.f;  // placate compiler on first touch
        {
            float v0 = emb[b * EE + tid];
            float v1 = emb[b * EE + tid + 256];
            se[tid] = v0 / (1.0f + __expf(-v0));
            se[tid + 256] = v1 / (1.0f + __expf(-v1));
        }
        __syncthreads();
        int cl = tid & 63;
        int ks = tid >> 6;   // 0..3, each covers 128 e's
        const float* W;
        const float* Bv;
        float* dst;
        int c0;
        if (chunk < 4)      { c0 = chunk * 64;       W = m1w; Bv = m1b; dst = bias1 + b * CIN + c0; }
        else if (chunk < 6) { c0 = (chunk - 4) * 64; W = m2w; Bv = m2b; dst = bias2 + b * COUT + c0; }
        else                { c0 = (chunk - 6) * 64; W = m3w; Bv = m3b; dst = bias3 + b * COUT + c0; }
        const float4* w4 = (const float4*)(W + (size_t)(c0 + cl) * EE + ks * 128);
        const float* sp = &se[ks * 128];
        float acc = 0.f;
        #pragma unroll
        for (int e4 = 0; e4 < 32; ++e4) {
            float4 v = w4[e4];
            acc += sp[e4 * 4 + 0] * v.x + sp[e4 * 4 + 1] * v.y +
                   sp[e4 * 4 + 2] * v.z + sp[e4 * 4 + 3] * v.w;
        }
        red[tid] = acc;
        __syncthreads();
        if (ks == 0)
            dst[cl] = red[cl] + red[cl + 64] + red[cl + 128] + red[cl + 192] + Bv[c0 + cl];
    } else {
        int o = bid - 128;     // output channel
        int i = tid;           // input channel 0..255
        float wv[9];
        float asum = 0.f;
        const float* wp = conv_w + ((size_t)o * CIN + i) * 9;
        #pragma unroll
        for (int k = 0; k < 9; ++k) {
            float v = wp[k];
            wv[k] = v;
            asum += fabsf(v);
        }
        int wave = tid >> 6;
        #pragma unroll
        for (int k = 0; k < 9; ++k) {
            unsigned long long m = __ballot(wv[k] > 0.0f);
            if ((tid & 63) == 0) wpack[((size_t)o * 9 + k) * 4 + wave] = m;
        }
        red[tid] = asum;
        __syncthreads();
        for (int s = 128; s > 0; s >>= 1) {
            if (tid < s) red[tid] += red[tid + s];
            __syncthreads();
        }
        if (tid == 0) {
            float sc = red[0] * (1.0f / 2304.0f);
            float inv = bn_g[o] * rsqrtf(bn_v[o] + 1e-5f);
            A[o] = sc * inv;
            B0[o] = (conv_b[o] - bn_m[o]) * inv + bn_b[o];
        }
    }
}

// One block per (b,h) row. 256 threads = 64 w-lanes x 4 channel-quarters.
__global__ __launch_bounds__(256) void pack_k(
    const float* __restrict__ x, const float* __restrict__ bias1,
    unsigned long long* __restrict__ xpack)
{
    int bid = blockIdx.x;          // b*64 + h
    int b = bid >> 6;
    int h = bid & 63;
    int tid = threadIdx.x;
    int w = tid & 63;
    int q = tid >> 6;              // channel quarter, wave-uniform
    __shared__ float sb[CIN];
    sb[tid] = bias1[b * CIN + tid];
    __syncthreads();
    const float* xp = x + ((size_t)b * CIN + (size_t)q * 64) * (HH * WW) + (size_t)h * WW + w;
    const float* bb = &sb[q * 64];
    unsigned long long m = 0;
    #pragma unroll
    for (int c = 0; c < 64; ++c) {
        if (xp[(size_t)c * (HH * WW)] + bb[c] > 0.f) m |= 1ull << c;
    }
    xpack[((((size_t)b * HH + h) * WW + w) << 2) + q] = m;
}

// 2048 blocks: bid = b*128 + h*2 + half. 256 threads = 64 w x 4 og-waves.
// oo-major: xpack neighborhood resident in VGPRs, per-oo weights are 36
// contiguous u64 (288 B) of wave-uniform scalar loads.
__global__ __launch_bounds__(256, 4) void main_k(
    const unsigned long long* __restrict__ wpack,   // [128][9][4]
    const unsigned long long* __restrict__ xpack,   // [16][64][64][4]
    const float* __restrict__ x,
    const float* __restrict__ A, const float* __restrict__ B0,
    const float* __restrict__ bias2, const float* __restrict__ bias3,
    const float* __restrict__ prelu_a,
    float* __restrict__ out)
{
    int bid = blockIdx.x;
    int half = bid & 1;
    int h = (bid >> 1) & 63;
    int b = bid >> 7;
    int tid = threadIdx.x;
    int w = tid & 63;
    int og = tid >> 6;
    int ou = __builtin_amdgcn_readfirstlane(half * 64 + og * 16);  // uniform o base

    int cm0 = (w >= 1) ? -1 : 0;
    int cm2 = (w <= 62) ? -1 : 0;
    int rm0 = (h >= 1) ? -1 : 0;   // block-uniform
    int rm2 = (h <= 62) ? -1 : 0;
    int msk[9];
    msk[0] = rm0 & cm0; msk[1] = rm0; msk[2] = rm0 & cm2;
    msk[3] = cm0;       msk[4] = -1;  msk[5] = cm2;
    msk[6] = rm2 & cm0; msk[7] = rm2; msk[8] = rm2 & cm2;
    int nv = (1 - rm0 - rm2) * (1 - cm0 - cm2);

    // Load 3x3 xpack neighborhood into registers (72 VGPRs), clamped addrs.
    unsigned long long xv[9][4];
    #pragma unroll
    for (int r = 0; r < 3; ++r) {
        int hc = min(max(h + r - 1, 0), HH - 1);
        #pragma unroll
        for (int dw = 0; dw < 3; ++dw) {
            int wc = min(max(w + dw - 1, 0), WW - 1);
            const unsigned long long* p =
                xpack + ((((size_t)b * HH + hc) * WW + wc) << 2);
            xv[r * 3 + dw][0] = p[0];
            xv[r * 3 + dw][1] = p[1];
            xv[r * 3 + dw][2] = p[2];
            xv[r * 3 + dw][3] = p[3];
        }
    }

    #pragma unroll
    for (int oo = 0; oo < 16; ++oo) {
        int o = ou + oo;  // uniform
        const unsigned long long* wp = wpack + (size_t)o * 36;
        float r0 = x[(((size_t)b * CIN + 2 * o) * HH + h) * WW + w];
        float r1 = x[(((size_t)b * CIN + 2 * o + 1) * HH + h) * WW + w];
        int P = 0;
        #pragma unroll
        for (int t = 0; t < 9; ++t) {
            int p = __popcll(xv[t][0] ^ wp[t * 4 + 0]) +
                    __popcll(xv[t][1] ^ wp[t * 4 + 1]) +
                    __popcll(xv[t][2] ^ wp[t * 4 + 2]) +
                    __popcll(xv[t][3] ^ wp[t * 4 + 3]);
            P += msk[t] & p;
        }
        float tv = (float)(nv * 256 - 2 * P) * A[o] + B0[o];
        tv += 0.5f * (r0 + r1) + bias2[b * COUT + o];
        tv = tv > 0.f ? tv : prelu_a[o] * tv;
        out[(((size_t)b * COUT + o) * HH + h) * WW + w] = tv + bias3[b * COUT + o];
    }
}

extern "C" void kernel_launch(void* const* d_in, const int* in_sizes, int n_in,
                              void* d_out, int out_size, void* d_ws, size_t ws_size,
                              hipStream_t stream) {
    const float* x      = (const float*)d_in[0];
    const float* emb    = (const float*)d_in[1];
    const float* m1w    = (const float*)d_in[2];
    const float* m1b    = (const float*)d_in[3];
    const float* conv_w = (const float*)d_in[4];
    const float* conv_b = (const float*)d_in[5];
    const float* bn_g   = (const float*)d_in[6];
    const float* bn_b   = (const float*)d_in[7];
    const float* bn_m   = (const float*)d_in[8];
    const float* bn_v   = (const float*)d_in[9];
    const float* m2w    = (const float*)d_in[10];
    const float* m2b    = (const float*)d_in[11];
    const float* pa     = (const float*)d_in[12];
    const float* m3w    = (const float*)d_in[13];
    const float* m3b    = (const float*)d_in[14];
    float* out = (float*)d_out;

    char* ws = (char*)d_ws;
    float* bias1 = (float*)(ws + 0);
    float* bias2 = (float*)(ws + 16384);
    float* bias3 = (float*)(ws + 24576);
    float* Aarr  = (float*)(ws + 33280);
    float* B0arr = (float*)(ws + 33792);
    unsigned long long* wpack = (unsigned long long*)(ws + 34304);
    unsigned long long* xpack = (unsigned long long*)(ws + 71168);

    prep_k<<<256, 256, 0, stream>>>(emb, m1w, m1b, m2w, m2b, m3w, m3b,
                                    conv_w, conv_b, bn_g, bn_b, bn_m, bn_v,
                                    bias1, bias2, bias3, Aarr, B0arr, wpack);
    pack_k<<<BB * HH, 256, 0, stream>>>(x, bias1, xpack);
    main_k<<<BB * HH * 2, 256, 0, stream>>>(wpack, xpack, x, Aarr, B0arr,
                                            bias2, bias3, pa, out);
}